// Round 9
// baseline (214.436 us; speedup 1.0000x reference)
//
#include <hip/hip_runtime.h>
#include <cmath>

// Problem constants
#define M_B   8
#define LQ    256
#define N_B   64
#define LR    512
#define COND  64
#define PRED  32
#define DH    128
#define QN    193      // LQ-COND+1
#define KN    417      // (LR-PRED)-COND+1
#define QPAD  256      // per-m padded q rows (8*256 = 2048 total)
#define KPAD  448      // padded kpos (14 chunks of 32)

typedef _Float16 half8 __attribute__((ext_vector_type(8)));
typedef float f32x16 __attribute__((ext_vector_type(16)));

__device__ __forceinline__ f32x16 mfma_f16(half8 a, half8 b, f32x16 c) {
    return __builtin_amdgcn_mfma_f32_32x32x16_f16(a, b, c, 0, 0, 0);
}
__device__ __forceinline__ f32x16 zero16() {
    f32x16 z;
    #pragma unroll
    for (int i = 0; i < 16; i++) z[i] = 0.f;
    return z;
}

#define GLOAD_LDS16(g, l) __builtin_amdgcn_global_load_lds( \
    (const __attribute__((address_space(1))) void*)(g), \
    (__attribute__((address_space(3))) void*)(l), 16, 0, 0)

// Force a float to live in a VGPR (blocks LDS-rematerialization of loads).
#define PIN_V(x) asm volatile("" : "+v"(x))

// ---------------- KA: fused feature kernel ----------------
// grid 480: blocks [0,448) = K/V features (n = b/7, chunk = b%7);
//           blocks [448,480) = Q features (id = b-448: m = id>>2, qc = id&3).
// lane kl = t&63 owns one kpos/qpos (window pinned in VGPRs), wave hq owns 32 h
// (weights via wave-uniform s_load). buf columns XOR-swizzled by h>>3.
// Scan = per-wave __shfl_up inclusive scan + LDS wave-offset combine (2 barriers).
__launch_bounds__(256, 2)
__global__ void kA_feat(const float* __restrict__ query, const float* __restrict__ ref,
                        const float* __restrict__ qw, const float* __restrict__ qb,
                        const float* __restrict__ kw, const float* __restrict__ kb,
                        const float* __restrict__ vw, const float* __restrict__ vb,
                        float* __restrict__ q_scale, float* __restrict__ qfeat,
                        _Float16* __restrict__ qg,
                        _Float16* __restrict__ kg, float* __restrict__ vfeat) {
    __shared__ float x[512];
    __shared__ float s[512];
    __shared__ float wtot[4];
    __shared__ float buf[128 * 65];
    const int t = threadIdx.x;
    const int kl = t & 63;
    const int lane = t & 63, wv = t >> 6;
    const int hq = __builtin_amdgcn_readfirstlane(t >> 6);

    if (blockIdx.x < 448) {
        // ================= K/V branch =================
        const int n = blockIdx.x / 7, chunk = blockIdx.x % 7;
        // wave-scan of ref row n (512): thread owns elems 2t, 2t+1
        const float2 pr = *(const float2*)&ref[n * 512 + 2 * t];
        const float a = pr.x, b = pr.y;
        const float ls = a + b;
        float sc = ls;
        #pragma unroll
        for (int d = 1; d < 64; d <<= 1) {
            float v = __shfl_up(sc, d, 64);
            if (lane >= d) sc += v;
        }
        if (lane == 63) wtot[wv] = sc;
        x[2 * t] = a; x[2 * t + 1] = b;
        __syncthreads();
        float woff = 0.f;
        #pragma unroll
        for (int w2 = 0; w2 < 3; w2++) if (w2 < wv) woff += wtot[w2];
        const float excl = woff + sc - ls;
        s[2 * t] = excl + a;
        s[2 * t + 1] = excl + a + b;
        __syncthreads();

        const int kp = chunk * 64 + kl;
        const bool vkp = kp < KN;
        float csw[64];
        float mn = INFINITY, mx = -INFINITY;
        #pragma unroll
        for (int j = 0; j < 64; j++) {
            float v = s[kp + j];             // kp+63 <= 510, in range
            csw[j] = v;
            mn = fminf(mn, v);
            mx = fmaxf(mx, v);
        }
        float scv = mx - mn; if (scv == 0.f) scv = 1.f;
        const float inv = 1.f / scv;
        // pre-subtract mn (kills the wsum term) and pin window in VGPRs
        #pragma unroll
        for (int j = 0; j < 64; j++) { csw[j] -= mn; PIN_V(csw[j]); }

        // ---- k features: kval = (sum_j w*(cs-mn)) * inv + kb ----
        for (int hh = 0; hh < 32; hh++) {
            const int h = hq * 32 + hh;      // wave-uniform -> s_load weights
            const float* wrow = kw + h * 64;
            float a0 = 0.f, a1 = 0.f, a2 = 0.f, a3 = 0.f;
            #pragma unroll
            for (int j = 0; j < 64; j += 4) {
                a0 = fmaf(wrow[j],     csw[j],     a0);
                a1 = fmaf(wrow[j + 1], csw[j + 1], a1);
                a2 = fmaf(wrow[j + 2], csw[j + 2], a2);
                a3 = fmaf(wrow[j + 3], csw[j + 3], a3);
            }
            float kraw = (a0 + a1) + (a2 + a3);
            float kval = vkp ? kraw * inv + kb[h] : 0.f;
            buf[h * 65 + (kl ^ (h >> 3))] = kval;
        }
        __syncthreads();
        // emit kg: 64 kp x 32 granules (16 hi + 16 lo), swizzled by kp&31
        {
            const size_t nb = ((size_t)n * KPAD + chunk * 64) * 256;
            #pragma unroll
            for (int r = 0; r < 8; r++) {
                int task = r * 256 + t;
                int kp_l = task >> 5, g = task & 31;
                int cb = g & 15, lo = g >> 4;
                half8 hv;
                #pragma unroll
                for (int jj = 0; jj < 8; jj++) {
                    float v = buf[(cb * 8 + jj) * 65 + (kp_l ^ cb)];
                    _Float16 hi = (_Float16)v;
                    hv[jj] = lo ? (_Float16)((v - (float)hi) * 1024.0f) : hi;
                }
                *(half8*)&kg[nb + (size_t)kp_l * 256 + ((size_t)(g ^ (kp_l & 31)) << 3)] = hv;
            }
        }
        __syncthreads();
        // ---- v features ----
        float refw[32];
        #pragma unroll
        for (int j = 0; j < 32; j++) {
            int ri = 64 + kp + j;
            refw[j] = (ri < 512) ? x[ri] : 0.f;
            PIN_V(refw[j]);
        }
        for (int hh = 0; hh < 32; hh++) {
            const int h = hq * 32 + hh;
            const float* vrow = vw + h * 32;
            float b0 = 0.f, b1 = 0.f;
            #pragma unroll
            for (int j = 0; j < 32; j += 2) {
                b0 = fmaf(vrow[j],     refw[j],     b0);
                b1 = fmaf(vrow[j + 1], refw[j + 1], b1);
            }
            float vval = vkp ? (b0 + b1) * inv + vb[h] : 0.f;
            buf[h * 65 + (kl ^ (h >> 3))] = vval;
        }
        __syncthreads();
        {
            const size_t vb0 = ((size_t)n * KPAD + chunk * 64) * 128;
            #pragma unroll
            for (int r = 0; r < 8; r++) {
                int idx = r * 256 + t;
                int kp_l = idx >> 5, c4 = idx & 31;
                float4 o;
                o.x = buf[(c4 * 4 + 0) * 65 + (kp_l ^ ((c4 * 4 + 0) >> 3))];
                o.y = buf[(c4 * 4 + 1) * 65 + (kp_l ^ ((c4 * 4 + 1) >> 3))];
                o.z = buf[(c4 * 4 + 2) * 65 + (kp_l ^ ((c4 * 4 + 2) >> 3))];
                o.w = buf[(c4 * 4 + 3) * 65 + (kp_l ^ ((c4 * 4 + 3) >> 3))];
                *(float4*)&vfeat[vb0 + (size_t)kp_l * 128 + c4 * 4] = o;
            }
        }
    } else {
        // ================= Q branch =================
        const int id = blockIdx.x - 448;
        const int m = id >> 2, qc = id & 3;
        // wave-scan of query row m (256): 1 elem/thread
        const float a = query[m * 256 + t];
        float sc = a;
        #pragma unroll
        for (int d = 1; d < 64; d <<= 1) {
            float v = __shfl_up(sc, d, 64);
            if (lane >= d) sc += v;
        }
        if (lane == 63) wtot[wv] = sc;
        __syncthreads();
        float woff = 0.f;
        #pragma unroll
        for (int w2 = 0; w2 < 3; w2++) if (w2 < wv) woff += wtot[w2];
        s[t] = woff + sc;
        __syncthreads();

        const int qpos = qc * 64 + kl;
        const bool vq = qpos < QN;
        const int base = vq ? qpos : (QN - 1);
        float csw[64];
        float mn = INFINITY, mx = -INFINITY;
        #pragma unroll
        for (int j = 0; j < 64; j++) {
            float v = s[base + j];
            csw[j] = v;
            mn = fminf(mn, v);
            mx = fmaxf(mx, v);
        }
        float sq = mx - mn; if (sq == 0.f) sq = 1.f;
        const float inv = 1.f / sq;
        if (t < 64) q_scale[m * QPAD + qpos] = vq ? sq : 1.f;
        #pragma unroll
        for (int j = 0; j < 64; j++) { csw[j] -= mn; PIN_V(csw[j]); }

        for (int hh = 0; hh < 32; hh++) {
            const int h = hq * 32 + hh;      // wave-uniform -> s_load weights
            const float* wrow = qw + h * 64;
            float a0 = 0.f, a1 = 0.f, a2 = 0.f, a3 = 0.f;
            #pragma unroll
            for (int j = 0; j < 64; j += 4) {
                a0 = fmaf(wrow[j],     csw[j],     a0);
                a1 = fmaf(wrow[j + 1], csw[j + 1], a1);
                a2 = fmaf(wrow[j + 2], csw[j + 2], a2);
                a3 = fmaf(wrow[j + 3], csw[j + 3], a3);
            }
            float raw = (a0 + a1) + (a2 + a3);
            float val = vq ? raw * inv + qb[h] : 0.f;
            buf[h * 65 + (kl ^ (h >> 3))] = val;
        }
        __syncthreads();
        // emit qfeat (coalesced float4)
        const size_t qb0 = ((size_t)m * QPAD + qc * 64) * 128;
        #pragma unroll
        for (int r = 0; r < 8; r++) {
            int idx = r * 256 + t;
            int qp_l = idx >> 5, c4 = idx & 31;
            float4 o;
            o.x = buf[(c4 * 4 + 0) * 65 + (qp_l ^ ((c4 * 4 + 0) >> 3))];
            o.y = buf[(c4 * 4 + 1) * 65 + (qp_l ^ ((c4 * 4 + 1) >> 3))];
            o.z = buf[(c4 * 4 + 2) * 65 + (qp_l ^ ((c4 * 4 + 2) >> 3))];
            o.w = buf[(c4 * 4 + 3) * 65 + (qp_l ^ ((c4 * 4 + 3) >> 3))];
            *(float4*)&qfeat[qb0 + (size_t)qp_l * 128 + c4 * 4] = o;
        }
        // emit qg frag-major hi/lo: h = c*16 + kh*8 + jj; fb = grp*16 + c*2 + lo
        #pragma unroll
        for (int r = 0; r < 8; r++) {
            int idx = r * 256 + t;
            int qp_l = idx >> 5, g = idx & 31;
            int c = g >> 2, kh = (g >> 1) & 1, lo = g & 1;
            half8 hv;
            #pragma unroll
            for (int jj = 0; jj < 8; jj++) {
                int h = c * 16 + kh * 8 + jj;
                float v = buf[h * 65 + (qp_l ^ (h >> 3))];
                _Float16 hi = (_Float16)v;
                hv[jj] = lo ? (_Float16)((v - (float)hi) * 1024.0f) : hi;
            }
            int qp2 = qc * 64 + qp_l;
            int grp = (m << 3) | (qp2 >> 5);
            size_t fb = (size_t)(grp * 16 + c * 2 + lo);
            *(half8*)&qg[fb * 512 + (size_t)(kh * 32 + (qp2 & 31)) * 8] = hv;
        }
    }
}

// ---------------- K3: split-f16 MFMA score matmul + max/argmax ----------------
// R2-proven loop, K-range split in two: grid = 2 half x 8 qt x 64 n = 1024 blocks
// (4 blocks/CU, 16 waves/CU at VGPR 128 + 32 KB LDS). Each block: 7 chunks of
// 32 kpos, double-buffered 16 KB LDS, plain __syncthreads. Output per (mq,n):
// float2/int2 pair indexed by half; k4 combines (half1 kp > half0 kp always).
__launch_bounds__(256, 2)
__global__ void k3_score(const _Float16* __restrict__ qg, const _Float16* __restrict__ kg,
                         float* __restrict__ bscore, int* __restrict__ bidx) {
    __shared__ _Float16 Kbuf[2][32 * 256];   // 16 KB each
    const int blk = blockIdx.x;
    const int n = blk & 63, qt = (blk >> 6) & 7, half = blk >> 9;
    const int t = threadIdx.x, w = t >> 6, l = t & 63;
    const int lrow = l & 31, khalf = l >> 5;

    // Q fragments: [r=2 row-groups of 32][c=8][hi/lo], 32-row-group global layout
    half8 qf[2][8][2];
    #pragma unroll
    for (int r = 0; r < 2; r++) {
        const int grp = (qt * 4 + w) * 2 + r;
        #pragma unroll
        for (int c = 0; c < 8; c++)
            #pragma unroll
            for (int h = 0; h < 2; h++)
                qf[r][c][h] = ((const half8*)qg)[(size_t)(grp * 16 + c * 2 + h) * 64 + l];
    }

    const _Float16* ksrc = kg + (size_t)n * KPAD * 256 + (size_t)half * 7 * (32 * 256);

    float best[2][16];
    unsigned bkt[4] = {0u, 0u, 0u, 0u};
    #pragma unroll
    for (int r = 0; r < 2; r++)
        #pragma unroll
        for (int g = 0; g < 16; g++) best[r][g] = -INFINITY;

    // stage chunk 0 (16 KB): wave-uniform base + lane*16
    #pragma unroll
    for (int rd = 0; rd < 4; rd++) {
        int e = (rd * 4 + w) * 512 + l * 8;
        GLOAD_LDS16(ksrc + e, &Kbuf[0][0] + e);
    }

    for (int kt = 0; kt < 7; kt++) {
        __syncthreads();                       // drains vmcnt -> chunk kt ready
        if (kt < 6) {
            const _Float16* src = ksrc + (size_t)(kt + 1) * (32 * 256);
            _Float16* dst = &Kbuf[(kt + 1) & 1][0];
            #pragma unroll
            for (int rd = 0; rd < 4; rd++) {
                int e = (rd * 4 + w) * 512 + l * 8;
                GLOAD_LDS16(src + e, dst + e);
            }
        }
        const _Float16* kb = &Kbuf[kt & 1][0];
        f32x16 accH[2], accL[2];
        accH[0] = zero16(); accH[1] = zero16();
        accL[0] = zero16(); accL[1] = zero16();
        #pragma unroll
        for (int c = 0; c < 8; c++) {
            half8 bh = *(const half8*)(kb + lrow * 256 + (((c * 2 + khalf) ^ lrow) * 8));
            half8 bl = *(const half8*)(kb + lrow * 256 + (((16 + c * 2 + khalf) ^ lrow) * 8));
            #pragma unroll
            for (int r = 0; r < 2; r++) {
                accH[r] = mfma_f16(qf[r][c][0], bh, accH[r]);
                accL[r] = mfma_f16(qf[r][c][0], bl, accL[r]);
                accL[r] = mfma_f16(qf[r][c][1], bh, accL[r]);
            }
        }
        const int sub = half * 7 + kt;         // 0..13, fits nibble
        const int kp = sub * 32 + lrow;
        const bool valid = kp < KN;
        #pragma unroll
        for (int r = 0; r < 2; r++) {
            #pragma unroll
            for (int g = 0; g < 16; g++) {
                float sv = fmaf(accL[r][g], 0.0009765625f, accH[r][g]);
                // strict > with ascending kp => numpy first-index tie-break per lane
                if (valid && (sv > best[r][g])) {
                    best[r][g] = sv;
                    const int slot = r * 16 + g;
                    const unsigned sh = (unsigned)(slot & 7) * 4u;
                    bkt[slot >> 3] = (bkt[slot >> 3] & ~(0xFu << sh)) | ((unsigned)sub << sh);
                }
            }
        }
    }

    // cross-lane argmax reduce within each 32-lane half
    #pragma unroll
    for (int r = 0; r < 2; r++) {
        #pragma unroll
        for (int g = 0; g < 16; g++) {
            float sv = best[r][g];
            const int slot = r * 16 + g;
            int sub = (int)((bkt[slot >> 3] >> ((slot & 7) * 4)) & 0xFu);
            int kp = sub * 32 + lrow;
            for (int msk = 1; msk < 32; msk <<= 1) {
                float os = __shfl_xor(sv, msk, 64);
                int okp = __shfl_xor(kp, msk, 64);
                if (os > sv || (os == sv && okp < kp)) { sv = os; kp = okp; }
            }
            if (lrow == 0) {
                int row = (g & 3) + 8 * (g >> 2) + 4 * khalf;
                int mq = (qt * 4 + w) * 64 + r * 32 + row;
                if ((mq & 255) < QN) {
                    bscore[(((size_t)mq * 64 + n) << 1) + half] = sv;
                    bidx[(((size_t)mq * 64 + n) << 1) + half] = kp;
                }
            }
        }
    }
}

// ---------------- K4: softmax + gather-weight V + projection + fused mc conv ----------------
// grid 386 blocks x 256 thr (one wave per qpos; 386*4 == 1544 exactly).
__global__ void k4_out(const float* __restrict__ query,
                       const float* __restrict__ qfeat, const float* __restrict__ vfeat,
                       const float* __restrict__ bscore, const int* __restrict__ bidx,
                       const float* __restrict__ q_scale,
                       const float* __restrict__ mw, const float* __restrict__ mb,
                       const float* __restrict__ mkey,
                       const float* __restrict__ ow, const float* __restrict__ ob,
                       float* __restrict__ out) {
    __shared__ float rsS[4][64];
    __shared__ int   idxS[4][64];
    __shared__ float wS[4][128];
    const int t = threadIdx.x, wv = t >> 6, l = t & 63;
    const int j = blockIdx.x * 4 + wv;       // 0..1543
    const int m = j / QN, qpos = j - m * QN;
    const int mq = m * QPAD + qpos;

    // combine the two K-halves (half1 kp always > half0 kp -> strict > keeps
    // numpy first-index tie-break)
    const float2 s2 = *(const float2*)&bscore[((size_t)mq * 64 + l) << 1];
    const int2  i2 = *(const int2*)&bidx[((size_t)mq * 64 + l) << 1];
    float s = s2.x; int idx = i2.x;
    if (s2.y > s) { s = s2.y; idx = i2.y; }

    float msv = qfeat[(size_t)mq * 128 + l] * mkey[l]
              + qfeat[(size_t)mq * 128 + 64 + l] * mkey[64 + l];
    #pragma unroll
    for (int msk = 1; msk < 64; msk <<= 1) msv += __shfl_xor(msv, msk, 64);
    float mx = s;
    #pragma unroll
    for (int msk = 1; msk < 64; msk <<= 1) mx = fmaxf(mx, __shfl_xor(mx, msk, 64));
    mx = fmaxf(mx, msv);
    float e = expf(s - mx);
    float sum = e;
    #pragma unroll
    for (int msk = 1; msk < 64; msk <<= 1) sum += __shfl_xor(sum, msk, 64);
    float ems = expf(msv - mx);
    float inv = 1.f / (sum + ems);
    float rs = e * inv, msw = ems * inv;

    rsS[wv][l] = rs; idxS[wv][l] = idx;
    __syncthreads();
    float ax = 0.f, ay = 0.f;
    #pragma unroll 8
    for (int nn = 0; nn < 64; nn++) {
        float r = rsS[wv][nn];
        int id = idxS[wv][nn];
        const float2 v = *(const float2*)&vfeat[((size_t)nn * KPAD + id) * 128 + 2 * l];
        ax = fmaf(r, v.x, ax);
        ay = fmaf(r, v.y, ay);
    }
    wS[wv][2 * l] = ax; wS[wv][2 * l + 1] = ay;
    __syncthreads();
    if (l < 32) {
        float p = 0.f;
        #pragma unroll
        for (int h4 = 0; h4 < 32; h4++) {
            const float4 wv4 = *(const float4*)&wS[wv][h4 * 4];
            const float4 o4 = *(const float4*)&ow[l * 128 + h4 * 4];
            p += wv4.x * o4.x + wv4.y * o4.y + wv4.z * o4.z + wv4.w * o4.w;
        }
        p += (1.f - msw) * ob[l];
        // fused mc conv: mc[m, 32+qpos+l] = mb + sum_j mw[j]*query[m, tpos+j-63]
        float mcv = mb[0];
        const int tpos = 32 + qpos + l;
        for (int jj = 0; jj < 64; jj++) {
            int qi = tpos + jj - 63;
            if (qi >= 0) mcv = fmaf(mw[jj], query[m * 256 + qi], mcv);
        }
        float outv = q_scale[mq] * p + msw * mcv;
        out[(size_t)j * 32 + l] = outv;
    }
}

extern "C" void kernel_launch(void* const* d_in, const int* in_sizes, int n_in,
                              void* d_out, int out_size, void* d_ws, size_t ws_size,
                              hipStream_t stream) {
    const float* query = (const float*)d_in[0];
    const float* ref   = (const float*)d_in[1];
    const float* qw    = (const float*)d_in[2];
    const float* qb    = (const float*)d_in[3];
    const float* kw    = (const float*)d_in[4];
    const float* kb    = (const float*)d_in[5];
    const float* vw    = (const float*)d_in[6];
    const float* vb    = (const float*)d_in[7];
    const float* mw    = (const float*)d_in[8];
    const float* mb    = (const float*)d_in[9];
    const float* ow    = (const float*)d_in[10];
    const float* ob    = (const float*)d_in[11];
    const float* mkey  = (const float*)d_in[12];
    float* out = (float*)d_out;

    // workspace layout (floats), 16B-aligned; total 8390656 fl = 33.6 MB
    float* ws = (float*)d_ws;
    float* q_scale = ws;                          // 2048
    float* qfeat   = ws + 2048;                   // 262144 -> 264192
    float* bscore  = ws + 264192;                 // 262144 (2048*64*2) -> 526336
    int*   bidx    = (int*)(ws + 526336);         // 262144 -> 788480
    _Float16* qg   = (_Float16*)(ws + 788480);    // 524288 halfs -> 1050624
    _Float16* kg   = (_Float16*)(ws + 1050624);   // 7340032 halfs -> 4720640
    float* vfeat   = ws + 4720640;                // 3670016 -> 8390656

    hipLaunchKernelGGL(kA_feat, dim3(480), dim3(256), 0, stream,
                       query, ref, qw, qb, kw, kb, vw, vb,
                       q_scale, qfeat, qg, kg, vfeat);
    hipLaunchKernelGGL(k3_score, dim3(1024), dim3(256), 0, stream,
                       qg, kg, bscore, bidx);
    hipLaunchKernelGGL(k4_out, dim3(386), dim3(256), 0, stream,
                       query, qfeat, vfeat, bscore, bidx, q_scale, mw, mb, mkey, ow, ob, out);
}

// Round 11
// 198.723 us; speedup vs baseline: 1.0791x; 1.0791x over previous
//
#include <hip/hip_runtime.h>
#include <cmath>

// Problem constants
#define M_B   8
#define LQ    256
#define N_B   64
#define LR    512
#define COND  64
#define PRED  32
#define DH    128
#define QN    193      // LQ-COND+1
#define KN    417      // (LR-PRED)-COND+1
#define QPAD  256      // per-m padded q rows (8*256 = 2048 total)
#define KPAD  448      // padded kpos (14 chunks of 32)

typedef _Float16 half8 __attribute__((ext_vector_type(8)));
typedef float f32x16 __attribute__((ext_vector_type(16)));

__device__ __forceinline__ f32x16 mfma_f16(half8 a, half8 b, f32x16 c) {
    return __builtin_amdgcn_mfma_f32_32x32x16_f16(a, b, c, 0, 0, 0);
}
__device__ __forceinline__ f32x16 zero16() {
    f32x16 z;
    #pragma unroll
    for (int i = 0; i < 16; i++) z[i] = 0.f;
    return z;
}

#define GLOAD_LDS16(g, l) __builtin_amdgcn_global_load_lds( \
    (const __attribute__((address_space(1))) void*)(g), \
    (__attribute__((address_space(3))) void*)(l), 16, 0, 0)

// Force a float to live in a VGPR (blocks LDS-rematerialization of loads).
#define PIN_V(x) asm volatile("" : "+v"(x))

// ---------------- KA: fused feature kernel ----------------
// grid 480: blocks [0,448) = K/V features (n = b/7, chunk = b%7);
//           blocks [448,480) = Q features (id = b-448: m = id>>2, qc = id&3).
// lane kl = t&63 owns one kpos/qpos (window pinned in VGPRs), wave hq owns 32 h
// (weights via wave-uniform s_load). buf columns XOR-swizzled by h>>3.
__launch_bounds__(256, 2)
__global__ void kA_feat(const float* __restrict__ query, const float* __restrict__ ref,
                        const float* __restrict__ qw, const float* __restrict__ qb,
                        const float* __restrict__ kw, const float* __restrict__ kb,
                        const float* __restrict__ vw, const float* __restrict__ vb,
                        float* __restrict__ q_scale, float* __restrict__ qfeat,
                        _Float16* __restrict__ qg,
                        _Float16* __restrict__ kg, float* __restrict__ vfeat) {
    __shared__ float x[512];
    __shared__ float s[512];
    __shared__ float P[256];
    __shared__ float buf[128 * 65];
    const int t = threadIdx.x;
    const int kl = t & 63;
    const int hq = __builtin_amdgcn_readfirstlane(t >> 6);

    if (blockIdx.x < 448) {
        // ================= K/V branch =================
        const int n = blockIdx.x / 7, chunk = blockIdx.x % 7;
        // pair-scan of ref row n (512)
        x[t] = ref[n * 512 + t];
        x[t + 256] = ref[n * 512 + t + 256];
        __syncthreads();
        P[t] = x[2 * t] + x[2 * t + 1];
        __syncthreads();
        for (int off = 1; off < 256; off <<= 1) {
            float v = (t >= off) ? P[t - off] : 0.f;
            __syncthreads();
            P[t] += v;
            __syncthreads();
        }
        s[2 * t + 1] = P[t];
        s[2 * t]     = P[t] - x[2 * t + 1];
        __syncthreads();

        const int kp = chunk * 64 + kl;
        const bool vkp = kp < KN;
        float csw[64];
        float mn = INFINITY, mx = -INFINITY;
        #pragma unroll
        for (int j = 0; j < 64; j++) {
            float v = s[kp + j];             // kp+63 <= 510, in range
            csw[j] = v;
            mn = fminf(mn, v);
            mx = fmaxf(mx, v);
        }
        float scv = mx - mn; if (scv == 0.f) scv = 1.f;
        const float inv = 1.f / scv;
        // pre-subtract mn (kills the wsum term) and pin window in VGPRs
        #pragma unroll
        for (int j = 0; j < 64; j++) { csw[j] -= mn; PIN_V(csw[j]); }

        // ---- k features: kval = (sum_j w*(cs-mn)) * inv + kb ----
        for (int hh = 0; hh < 32; hh++) {
            const int h = hq * 32 + hh;      // wave-uniform -> s_load weights
            const float* wrow = kw + h * 64;
            float a0 = 0.f, a1 = 0.f, a2 = 0.f, a3 = 0.f;
            #pragma unroll
            for (int j = 0; j < 64; j += 4) {
                a0 = fmaf(wrow[j],     csw[j],     a0);
                a1 = fmaf(wrow[j + 1], csw[j + 1], a1);
                a2 = fmaf(wrow[j + 2], csw[j + 2], a2);
                a3 = fmaf(wrow[j + 3], csw[j + 3], a3);
            }
            float kraw = (a0 + a1) + (a2 + a3);
            float kval = vkp ? kraw * inv + kb[h] : 0.f;
            buf[h * 65 + (kl ^ (h >> 3))] = kval;
        }
        __syncthreads();
        // emit kg: 64 kp x 32 granules (16 hi + 16 lo), swizzled by kp&31
        {
            const size_t nb = ((size_t)n * KPAD + chunk * 64) * 256;
            #pragma unroll
            for (int r = 0; r < 8; r++) {
                int task = r * 256 + t;
                int kp_l = task >> 5, g = task & 31;
                int cb = g & 15, lo = g >> 4;
                half8 hv;
                #pragma unroll
                for (int jj = 0; jj < 8; jj++) {
                    float v = buf[(cb * 8 + jj) * 65 + (kp_l ^ cb)];
                    _Float16 hi = (_Float16)v;
                    hv[jj] = lo ? (_Float16)((v - (float)hi) * 1024.0f) : hi;
                }
                *(half8*)&kg[nb + (size_t)kp_l * 256 + ((size_t)(g ^ (kp_l & 31)) << 3)] = hv;
            }
        }
        __syncthreads();
        // ---- v features ----
        float refw[32];
        #pragma unroll
        for (int j = 0; j < 32; j++) {
            int ri = 64 + kp + j;
            refw[j] = (ri < 512) ? x[ri] : 0.f;
            PIN_V(refw[j]);
        }
        for (int hh = 0; hh < 32; hh++) {
            const int h = hq * 32 + hh;
            const float* vrow = vw + h * 32;
            float b0 = 0.f, b1 = 0.f;
            #pragma unroll
            for (int j = 0; j < 32; j += 2) {
                b0 = fmaf(vrow[j],     refw[j],     b0);
                b1 = fmaf(vrow[j + 1], refw[j + 1], b1);
            }
            float vval = vkp ? (b0 + b1) * inv + vb[h] : 0.f;
            buf[h * 65 + (kl ^ (h >> 3))] = vval;
        }
        __syncthreads();
        {
            const size_t vb0 = ((size_t)n * KPAD + chunk * 64) * 128;
            #pragma unroll
            for (int r = 0; r < 8; r++) {
                int idx = r * 256 + t;
                int kp_l = idx >> 5, c4 = idx & 31;
                float4 o;
                o.x = buf[(c4 * 4 + 0) * 65 + (kp_l ^ ((c4 * 4 + 0) >> 3))];
                o.y = buf[(c4 * 4 + 1) * 65 + (kp_l ^ ((c4 * 4 + 1) >> 3))];
                o.z = buf[(c4 * 4 + 2) * 65 + (kp_l ^ ((c4 * 4 + 2) >> 3))];
                o.w = buf[(c4 * 4 + 3) * 65 + (kp_l ^ ((c4 * 4 + 3) >> 3))];
                *(float4*)&vfeat[vb0 + (size_t)kp_l * 128 + c4 * 4] = o;
            }
        }
    } else {
        // ================= Q branch =================
        const int id = blockIdx.x - 448;
        const int m = id >> 2, qc = id & 3;
        // inclusive scan of query row m (256)
        s[t] = query[m * 256 + t];
        __syncthreads();
        for (int off = 1; off < 256; off <<= 1) {
            float v = (t >= off) ? s[t - off] : 0.f;
            __syncthreads();
            s[t] += v;
            __syncthreads();
        }
        const int qpos = qc * 64 + kl;
        const bool vq = qpos < QN;
        const int base = vq ? qpos : (QN - 1);
        float csw[64];
        float mn = INFINITY, mx = -INFINITY;
        #pragma unroll
        for (int j = 0; j < 64; j++) {
            float v = s[base + j];
            csw[j] = v;
            mn = fminf(mn, v);
            mx = fmaxf(mx, v);
        }
        float sc = mx - mn; if (sc == 0.f) sc = 1.f;
        const float inv = 1.f / sc;
        if (t < 64) q_scale[m * QPAD + qpos] = vq ? sc : 1.f;
        #pragma unroll
        for (int j = 0; j < 64; j++) { csw[j] -= mn; PIN_V(csw[j]); }

        for (int hh = 0; hh < 32; hh++) {
            const int h = hq * 32 + hh;      // wave-uniform -> s_load weights
            const float* wrow = qw + h * 64;
            float a0 = 0.f, a1 = 0.f, a2 = 0.f, a3 = 0.f;
            #pragma unroll
            for (int j = 0; j < 64; j += 4) {
                a0 = fmaf(wrow[j],     csw[j],     a0);
                a1 = fmaf(wrow[j + 1], csw[j + 1], a1);
                a2 = fmaf(wrow[j + 2], csw[j + 2], a2);
                a3 = fmaf(wrow[j + 3], csw[j + 3], a3);
            }
            float raw = (a0 + a1) + (a2 + a3);
            float val = vq ? raw * inv + qb[h] : 0.f;
            buf[h * 65 + (kl ^ (h >> 3))] = val;
        }
        __syncthreads();
        // emit qfeat (coalesced float4)
        const size_t qb0 = ((size_t)m * QPAD + qc * 64) * 128;
        #pragma unroll
        for (int r = 0; r < 8; r++) {
            int idx = r * 256 + t;
            int qp_l = idx >> 5, c4 = idx & 31;
            float4 o;
            o.x = buf[(c4 * 4 + 0) * 65 + (qp_l ^ ((c4 * 4 + 0) >> 3))];
            o.y = buf[(c4 * 4 + 1) * 65 + (qp_l ^ ((c4 * 4 + 1) >> 3))];
            o.z = buf[(c4 * 4 + 2) * 65 + (qp_l ^ ((c4 * 4 + 2) >> 3))];
            o.w = buf[(c4 * 4 + 3) * 65 + (qp_l ^ ((c4 * 4 + 3) >> 3))];
            *(float4*)&qfeat[qb0 + (size_t)qp_l * 128 + c4 * 4] = o;
        }
        // emit qg frag-major hi/lo: h = c*16 + kh*8 + jj; fb = grp*16 + c*2 + lo
        #pragma unroll
        for (int r = 0; r < 8; r++) {
            int idx = r * 256 + t;
            int qp_l = idx >> 5, g = idx & 31;
            int c = g >> 2, kh = (g >> 1) & 1, lo = g & 1;
            half8 hv;
            #pragma unroll
            for (int jj = 0; jj < 8; jj++) {
                int h = c * 16 + kh * 8 + jj;
                float v = buf[h * 65 + (qp_l ^ (h >> 3))];
                _Float16 hi = (_Float16)v;
                hv[jj] = lo ? (_Float16)((v - (float)hi) * 1024.0f) : hi;
            }
            int qp2 = qc * 64 + qp_l;
            int grp = (m << 3) | (qp2 >> 5);
            size_t fb = (size_t)(grp * 16 + c * 2 + lo);
            *(half8*)&qg[fb * 512 + (size_t)(kh * 32 + (qp2 & 31)) * 8] = hv;
        }
    }
}

// ---------------- K3: split-f16 MFMA score matmul + max/argmax ----------------
// R2-proven shape: 64 q-rows per wave (qf[2][8][2]), 32-kpos chunks, 16 KB x2 LDS,
// 14 barriers; grid 8 qt x 64 n = 512 blocks.
// R11 deltas: software-pipelined B-frag ds_reads (c+1 issued before c's MFMAs)
// and MFMA order accH0,accH1,accL0,accL1,accL0,accL1 (dependent accL updates
// separated by distance 2 instead of back-to-back).
__launch_bounds__(256, 2)
__global__ void k3_score(const _Float16* __restrict__ qg, const _Float16* __restrict__ kg,
                         float* __restrict__ bscore, int* __restrict__ bidx) {
    __shared__ _Float16 Kbuf[2][32 * 256];   // 16 KB each
    const int blk = blockIdx.x;
    const int n = blk & 63, qt = blk >> 6;
    const int t = threadIdx.x, w = t >> 6, l = t & 63;
    const int lrow = l & 31, khalf = l >> 5;

    // Q fragments: [r=2 row-groups of 32][c=8][hi/lo], 32-row-group global layout
    half8 qf[2][8][2];
    #pragma unroll
    for (int r = 0; r < 2; r++) {
        const int grp = (qt * 4 + w) * 2 + r;
        #pragma unroll
        for (int c = 0; c < 8; c++)
            #pragma unroll
            for (int h = 0; h < 2; h++)
                qf[r][c][h] = ((const half8*)qg)[(size_t)(grp * 16 + c * 2 + h) * 64 + l];
    }

    const _Float16* ksrc = kg + (size_t)n * KPAD * 256;

    float best[2][16];
    unsigned bkt[4] = {0u, 0u, 0u, 0u};
    #pragma unroll
    for (int r = 0; r < 2; r++)
        #pragma unroll
        for (int g = 0; g < 16; g++) best[r][g] = -INFINITY;

    // stage chunk 0 (16 KB): wave-uniform base + lane*16
    #pragma unroll
    for (int rd = 0; rd < 4; rd++) {
        int e = (rd * 4 + w) * 512 + l * 8;
        GLOAD_LDS16(ksrc + e, &Kbuf[0][0] + e);
    }

    for (int kt = 0; kt < 14; kt++) {
        __syncthreads();                       // drains vmcnt -> chunk kt ready
        if (kt < 13) {
            const _Float16* src = ksrc + (size_t)(kt + 1) * (32 * 256);
            _Float16* dst = &Kbuf[(kt + 1) & 1][0];
            #pragma unroll
            for (int rd = 0; rd < 4; rd++) {
                int e = (rd * 4 + w) * 512 + l * 8;
                GLOAD_LDS16(src + e, dst + e);
            }
        }
        const _Float16* krow = &Kbuf[kt & 1][0] + lrow * 256;
        f32x16 accH[2], accL[2];
        accH[0] = zero16(); accH[1] = zero16();
        accL[0] = zero16(); accL[1] = zero16();
        // software-pipelined B-frag reads: c+1 issued before c's MFMAs
        half8 bh = *(const half8*)(krow + ((khalf ^ lrow) * 8));
        half8 bl = *(const half8*)(krow + (((16 + khalf) ^ lrow) * 8));
        #pragma unroll
        for (int c = 0; c < 8; c++) {
            half8 nbh, nbl;
            if (c < 7) {
                nbh = *(const half8*)(krow + ((((c + 1) * 2 + khalf) ^ lrow) * 8));
                nbl = *(const half8*)(krow + (((16 + (c + 1) * 2 + khalf) ^ lrow) * 8));
            }
            accH[0] = mfma_f16(qf[0][c][0], bh, accH[0]);
            accH[1] = mfma_f16(qf[1][c][0], bh, accH[1]);
            accL[0] = mfma_f16(qf[0][c][0], bl, accL[0]);
            accL[1] = mfma_f16(qf[1][c][0], bl, accL[1]);
            accL[0] = mfma_f16(qf[0][c][1], bh, accL[0]);
            accL[1] = mfma_f16(qf[1][c][1], bh, accL[1]);
            bh = nbh; bl = nbl;
        }
        const int kp = kt * 32 + lrow;
        const bool valid = kp < KN;
        #pragma unroll
        for (int r = 0; r < 2; r++) {
            #pragma unroll
            for (int g = 0; g < 16; g++) {
                float sv = fmaf(accL[r][g], 0.0009765625f, accH[r][g]);
                // strict > with ascending kp => numpy first-index tie-break per lane
                if (valid && (sv > best[r][g])) {
                    best[r][g] = sv;
                    const int slot = r * 16 + g;
                    const unsigned sh = (unsigned)(slot & 7) * 4u;
                    bkt[slot >> 3] = (bkt[slot >> 3] & ~(0xFu << sh)) | ((unsigned)kt << sh);
                }
            }
        }
    }

    // cross-lane argmax reduce within each 32-lane half
    #pragma unroll
    for (int r = 0; r < 2; r++) {
        #pragma unroll
        for (int g = 0; g < 16; g++) {
            float sv = best[r][g];
            const int slot = r * 16 + g;
            int ktb = (int)((bkt[slot >> 3] >> ((slot & 7) * 4)) & 0xFu);
            int kp = ktb * 32 + lrow;
            for (int msk = 1; msk < 32; msk <<= 1) {
                float os = __shfl_xor(sv, msk, 64);
                int okp = __shfl_xor(kp, msk, 64);
                if (os > sv || (os == sv && okp < kp)) { sv = os; kp = okp; }
            }
            if (lrow == 0) {
                int row = (g & 3) + 8 * (g >> 2) + 4 * khalf;
                int mq = (qt * 4 + w) * 64 + r * 32 + row;
                if ((mq & 255) < QN) {
                    bscore[(size_t)mq * 64 + n] = sv;
                    bidx[(size_t)mq * 64 + n] = kp;
                }
            }
        }
    }
}

// ---------------- K4: softmax + gather-weight V + projection + fused mc conv ----------------
// grid 386 blocks x 256 thr (one wave per qpos; 386*4 == 1544 exactly).
__global__ void k4_out(const float* __restrict__ query,
                       const float* __restrict__ qfeat, const float* __restrict__ vfeat,
                       const float* __restrict__ bscore, const int* __restrict__ bidx,
                       const float* __restrict__ q_scale,
                       const float* __restrict__ mw, const float* __restrict__ mb,
                       const float* __restrict__ mkey,
                       const float* __restrict__ ow, const float* __restrict__ ob,
                       float* __restrict__ out) {
    __shared__ float rsS[4][64];
    __shared__ int   idxS[4][64];
    __shared__ float wS[4][128];
    const int t = threadIdx.x, wv = t >> 6, l = t & 63;
    const int j = blockIdx.x * 4 + wv;       // 0..1543
    const int m = j / QN, qpos = j - m * QN;
    const int mq = m * QPAD + qpos;

    float s = bscore[(size_t)mq * 64 + l];
    int idx = bidx[(size_t)mq * 64 + l];
    float msv = qfeat[(size_t)mq * 128 + l] * mkey[l]
              + qfeat[(size_t)mq * 128 + 64 + l] * mkey[64 + l];
    #pragma unroll
    for (int msk = 1; msk < 64; msk <<= 1) msv += __shfl_xor(msv, msk, 64);
    float mx = s;
    #pragma unroll
    for (int msk = 1; msk < 64; msk <<= 1) mx = fmaxf(mx, __shfl_xor(mx, msk, 64));
    mx = fmaxf(mx, msv);
    float e = expf(s - mx);
    float sum = e;
    #pragma unroll
    for (int msk = 1; msk < 64; msk <<= 1) sum += __shfl_xor(sum, msk, 64);
    float ems = expf(msv - mx);
    float inv = 1.f / (sum + ems);
    float rs = e * inv, msw = ems * inv;

    rsS[wv][l] = rs; idxS[wv][l] = idx;
    __syncthreads();
    float ax = 0.f, ay = 0.f;
    #pragma unroll 8
    for (int nn = 0; nn < 64; nn++) {
        float r = rsS[wv][nn];
        int id = idxS[wv][nn];
        const float2 v = *(const float2*)&vfeat[((size_t)nn * KPAD + id) * 128 + 2 * l];
        ax = fmaf(r, v.x, ax);
        ay = fmaf(r, v.y, ay);
    }
    wS[wv][2 * l] = ax; wS[wv][2 * l + 1] = ay;
    __syncthreads();
    if (l < 32) {
        float p = 0.f;
        #pragma unroll
        for (int h4 = 0; h4 < 32; h4++) {
            const float4 wv4 = *(const float4*)&wS[wv][h4 * 4];
            const float4 o4 = *(const float4*)&ow[l * 128 + h4 * 4];
            p += wv4.x * o4.x + wv4.y * o4.y + wv4.z * o4.z + wv4.w * o4.w;
        }
        p += (1.f - msw) * ob[l];
        // fused mc conv: mc[m, 32+qpos+l] = mb + sum_j mw[j]*query[m, tpos+j-63]
        float mcv = mb[0];
        const int tpos = 32 + qpos + l;
        for (int jj = 0; jj < 64; jj++) {
            int qi = tpos + jj - 63;
            if (qi >= 0) mcv = fmaf(mw[jj], query[m * 256 + qi], mcv);
        }
        float outv = q_scale[mq] * p + msw * mcv;
        out[(size_t)j * 32 + l] = outv;
    }
}

extern "C" void kernel_launch(void* const* d_in, const int* in_sizes, int n_in,
                              void* d_out, int out_size, void* d_ws, size_t ws_size,
                              hipStream_t stream) {
    const float* query = (const float*)d_in[0];
    const float* ref   = (const float*)d_in[1];
    const float* qw    = (const float*)d_in[2];
    const float* qb    = (const float*)d_in[3];
    const float* kw    = (const float*)d_in[4];
    const float* kb    = (const float*)d_in[5];
    const float* vw    = (const float*)d_in[6];
    const float* vb    = (const float*)d_in[7];
    const float* mw    = (const float*)d_in[8];
    const float* mb    = (const float*)d_in[9];
    const float* ow    = (const float*)d_in[10];
    const float* ob    = (const float*)d_in[11];
    const float* mkey  = (const float*)d_in[12];
    float* out = (float*)d_out;

    // workspace layout (floats), 16B-aligned; total 8128512 fl = 32.5 MB
    float* ws = (float*)d_ws;
    float* q_scale = ws;                          // 2048
    float* qfeat   = ws + 2048;                   // 262144 -> 264192
    float* bscore  = ws + 264192;                 // 131072 -> 395264
    int*   bidx    = (int*)(ws + 395264);         // 131072 -> 526336
    _Float16* qg   = (_Float16*)(ws + 526336);    // 524288 halfs -> 788480
    _Float16* kg   = (_Float16*)(ws + 788480);    // 7340032 halfs -> 4458496
    float* vfeat   = ws + 4458496;                // 3670016 -> 8128512

    hipLaunchKernelGGL(kA_feat, dim3(480), dim3(256), 0, stream,
                       query, ref, qw, qb, kw, kb, vw, vb,
                       q_scale, qfeat, qg, kg, vfeat);
    hipLaunchKernelGGL(k3_score, dim3(512), dim3(256), 0, stream,
                       qg, kg, bscore, bidx);
    hipLaunchKernelGGL(k4_out, dim3(386), dim3(256), 0, stream,
                       query, qfeat, vfeat, bscore, bidx, q_scale, mw, mb, mkey, ow, ob, out);
}